// Round 2
// baseline (14005.060 us; speedup 1.0000x reference)
//
#include <hip/hip_runtime.h>
#include <hip/hip_bf16.h>
#include <hip/hip_fp16.h>
#include <stdint.h>

// MambaBlock: B=64 T=2048 IN=256 STATE=512 OUT=256 K=3
// prep -> x->bf16 -> G1(silu proj) -> G2(conv-as-GEMM) -> BN stats
//      -> fold BN into Bm -> G3(U = conv_raw@Bm'+bias, [t][b][n] layout)
//      -> MFMA scan (8-wave; A kt0-9 in regs, kt10-15 streamed from L2 with
//         counted vmcnt; conflict-free red; asm barriers)
//      -> G4(Y = S@C', f16, +beta@C bias)

using bf16 = __hip_bfloat16;
typedef short    bf16x8 __attribute__((ext_vector_type(8)));
typedef float    f32x4v __attribute__((ext_vector_type(4)));
typedef _Float16 f16x8  __attribute__((ext_vector_type(8)));
typedef _Float16 f16x4  __attribute__((ext_vector_type(4)));

static __device__ inline unsigned short f2bf_bits(float f) {
  union { bf16 h; unsigned short u; } cv; cv.h = __float2bfloat16(f); return cv.u;
}
static __device__ inline float bflo(unsigned v) { return __builtin_bit_cast(float, v << 16); }
static __device__ inline float bfhi(unsigned v) { return __builtin_bit_cast(float, v & 0xFFFF0000u); }

// async global->LDS, 16B/lane; LDS dest = wave-uniform base + lane*16
static __device__ inline void glds16(const void* g, void* l) {
  __builtin_amdgcn_global_load_lds(
      (const __attribute__((address_space(1))) unsigned int*)g,
      (__attribute__((address_space(3))) unsigned int*)l, 16, 0, 0);
}

// barrier that drains ONLY lgkm (LDS) — leaves global loads/stores in flight.
#define ASM_BAR() asm volatile("s_waitcnt lgkmcnt(0)\n\ts_barrier" ::: "memory")

// counted vmcnt wait + scheduler fence (rule #18: MFMA can hoist past asm waits)
#define WAITV(N) do { asm volatile("s_waitcnt vmcnt(" #N ")"); \
                      __builtin_amdgcn_sched_barrier(0); } while (0)

// asm-volatile VMEM ops so the in-loop vmcnt queue is exactly what we issue.
template <int IMM>
static __device__ inline void gload_a(f16x8& d, const _Float16* p) {
  asm volatile("global_load_dwordx4 %0, %1, off offset:%2"
               : "=v"(d) : "v"(p), "i"(IMM));
}
static __device__ inline void gload_u2(uint2& d, const ushort* p) {
  asm volatile("global_load_dwordx2 %0, %1, off" : "=v"(d) : "v"(p));
}
static __device__ inline void gstore8(_Float16* p, f16x8 v) {
  asm volatile("global_store_dwordx4 %0, %1, off" :: "v"(p), "v"(v));
}

// ---------------- prep: zero sums + vpad edges, build weights ----------------
__global__ void kprep(const float* __restrict__ W_in, const float* __restrict__ conv_w,
                      const float* __restrict__ A, const float* __restrict__ C,
                      const float* __restrict__ lng, const float* __restrict__ lnb,
                      float* __restrict__ sums, bf16* __restrict__ vpad,
                      bf16* __restrict__ Wt, bf16* __restrict__ Wct,
                      _Float16* __restrict__ Ctf, _Float16* __restrict__ Afr,
                      float* __restrict__ cbeta, float* __restrict__ ybeta) {
  long idx = (long)blockIdx.x * 256 + threadIdx.x;
  if (idx < 1024) { sums[idx] = 0.f; return; }
  idx -= 1024;
  if (idx < 65536) {  // zero pad rows (t=-1, t=T) of vpad (64 x 2050 x 512)
    long b = idx >> 10, rem = idx & 1023, r = rem >> 9, col = rem & 511;
    long row = b * 2050 + (r ? 2049 : 0);
    vpad[row * 512 + col] = __float2bfloat16(0.f);
    return;
  }
  idx -= 65536;
  if (idx < 131072) { Wt[idx] = __float2bfloat16(W_in[idx]); return; } // (N=512,K=256)
  idx -= 131072;
  if (idx < 786432) { // Wct[o][kk*512+i] = conv_w[o,i,kk]   (N=512, K=1536)
    long o = idx / 1536, k = idx - o * 1536, kk = k >> 9, i = k & 511;
    Wct[idx] = __float2bfloat16(conv_w[(o * 512 + i) * 3 + kk]);
    return;
  }
  idx -= 786432;
  if (idx < 131072) { // Ctf[n][i] = C[i][n]*gamma[i]  f16  (N=256, K=512)
    long n = idx >> 9, i = idx & 511;
    Ctf[idx] = (_Float16)(C[i * 256 + n] * lng[i]);
    return;
  }
  idx -= 131072;
  if (idx < 262144) { // A' = diag(gamma)A -> MFMA fragment order (f16)
    long k = idx >> 9, n = idx & 511;
    long w = n >> 7, nt = (n >> 4) & 7, cc = n & 15;
    long kt = k >> 5, qq = (k & 31) >> 3, j = k & 7;
    Afr[(((w * 8 + nt) * 16 + kt) * 64 + (qq * 16 + cc)) * 8 + j] =
        (_Float16)(A[k * 512 + n] * lng[k]);
    return;
  }
  idx -= 262144;
  if (idx < 512) { // cbeta[n] = sum_k beta[k]*A[k][n]
    int n = (int)idx;
    float acc = 0.f;
    for (int k = 0; k < 512; ++k) acc += lnb[k] * A[(long)k * 512 + n];
    cbeta[n] = acc;
    return;
  }
  idx -= 512;
  if (idx < 256) { // ybeta[n] = sum_i beta[i]*C[i][n]
    int n = (int)idx;
    float acc = 0.f;
    for (int i = 0; i < 512; ++i) acc += lnb[i] * C[(long)i * 256 + n];
    ybeta[n] = acc;
  }
}

// ---------------- x fp32 -> bf16 ----------------
__global__ void kx(const float4* __restrict__ x, ushort4* __restrict__ xb) {
  size_t i = (size_t)blockIdx.x * 256 + threadIdx.x;
  float4 v = x[i];
  ushort4 o;
  o.x = f2bf_bits(v.x); o.y = f2bf_bits(v.y); o.z = f2bf_bits(v.z); o.w = f2bf_bits(v.w);
  xb[i] = o;
}

// ---------------- 128x128 MFMA GEMM, BK=64, 4 waves ----------------
// EPI 0: +bias, silu -> vpad scatter   EPI 1: bf16 (stride 512)
// EPI 2: +bias, bf16 -> U[t][b][n]     EPI 3: +bias, fp32 (stride 256)
template <int EPI, bool F16>
__global__ __launch_bounds__(256)
void kgemm(const bf16* __restrict__ Ag, long lda, long rowExtra,
           const bf16* __restrict__ Bg, int K,
           const float* __restrict__ bias, void* __restrict__ outp) {
  const int tid = threadIdx.x;
  const int lane = tid & 63;
  const int wv = tid >> 6;
  const int wm = wv >> 1, wn = wv & 1;
  const long m0 = (long)blockIdx.x * 128;
  const long n0 = (long)blockIdx.y * 128;
  __shared__ short At[128 * 64];
  __shared__ short Bt[128 * 64];
  f32x4v acc[4][4];
#pragma unroll
  for (int a = 0; a < 4; ++a)
#pragma unroll
    for (int b = 0; b < 4; ++b)
#pragma unroll
      for (int r = 0; r < 4; ++r) acc[a][b][r] = 0.f;

  const int rsub = lane >> 3;
  const int ksub = (lane & 7) * 8;

  for (int k0 = 0; k0 < K; k0 += 64) {
#pragma unroll
    for (int j = 0; j < 4; ++j) {
      const int c = wv * 4 + j;
      {
        long row = m0 + c * 8 + rsub;
        const bf16* gp = Ag + row * lda + (row >> 11) * rowExtra + k0 + ksub;
        glds16(gp, At + c * 512);
      }
      {
        long row = n0 + c * 8 + rsub;
        const bf16* gp = Bg + row * (long)K + k0 + ksub;
        glds16(gp, Bt + c * 512);
      }
    }
    __syncthreads();
#pragma unroll
    for (int h = 0; h < 2; ++h) {
      bf16x8 af[4], bf_[4];
      const int kb = h * 32 + (lane >> 4) * 8;
#pragma unroll
      for (int f = 0; f < 4; ++f) {
        af[f]  = *(const bf16x8*)(At + (wm * 64 + f * 16 + (lane & 15)) * 64 + kb);
        bf_[f] = *(const bf16x8*)(Bt + (wn * 64 + f * 16 + (lane & 15)) * 64 + kb);
      }
#pragma unroll
      for (int fm = 0; fm < 4; ++fm)
#pragma unroll
        for (int fn = 0; fn < 4; ++fn) {
          if constexpr (F16)
            acc[fm][fn] = __builtin_amdgcn_mfma_f32_16x16x32_f16(
                __builtin_bit_cast(f16x8, af[fm]), __builtin_bit_cast(f16x8, bf_[fn]),
                acc[fm][fn], 0, 0, 0);
          else
            acc[fm][fn] = __builtin_amdgcn_mfma_f32_16x16x32_bf16(af[fm], bf_[fn], acc[fm][fn], 0, 0, 0);
        }
    }
    __syncthreads();
  }

  const int q = lane >> 4, cL = lane & 15;
#pragma unroll
  for (int fm = 0; fm < 4; ++fm)
#pragma unroll
    for (int fn = 0; fn < 4; ++fn)
#pragma unroll
      for (int r = 0; r < 4; ++r) {
        const long m = m0 + wm * 64 + fm * 16 + q * 4 + r;
        const long n = n0 + wn * 64 + fn * 16 + cL;
        float v = acc[fm][fn][r];
        if constexpr (EPI == 0) {
          v += bias[n];
          const float s = v / (1.f + __expf(-v));
          const long row = (m >> 11) * 2050 + (m & 2047) + 1;
          ((bf16*)outp)[row * 512 + n] = __float2bfloat16(s);
        } else if constexpr (EPI == 1) {
          ((bf16*)outp)[m * 512 + n] = __float2bfloat16(v);
        } else if constexpr (EPI == 2) {
          // U layout [t][b][n]: m = b*2048+t  ->  row' = t*64 + b
          const long rowp = (m & 2047) * 64 + (m >> 11);
          ((bf16*)outp)[rowp * 512 + n] = __float2bfloat16(v + bias[n]);
        } else {
          ((float*)outp)[m * 256 + n] = v + bias[n];
        }
      }
}

// ---------------- BN stats ----------------
__global__ __launch_bounds__(512)
void bn_stats(const bf16* __restrict__ cr, float* __restrict__ sums) {
  const int tid = threadIdx.x;
  const long base = (long)blockIdx.x * 128 * 512;
  float s = 0.f, q = 0.f;
  for (int r = 0; r < 128; ++r) {
    float v = __bfloat162float(cr[base + (long)r * 512 + tid]);
    s += v; q += v * v;
  }
  atomicAdd(&sums[tid], s);
  atomicAdd(&sums[512 + tid], q);
}

__global__ void bn_finalize(const float* __restrict__ sums, const float* __restrict__ gamma,
                            const float* __restrict__ beta, float* __restrict__ scsh) {
  const int n = threadIdx.x;
  const float mu = sums[n] * (1.f / 131072.f);
  const float var = sums[512 + n] * (1.f / 131072.f) - mu * mu;
  const float sc = gamma[n] * rsqrtf(var + 1e-5f);
  scsh[n] = sc;
  scsh[512 + n] = beta[n] - mu * sc;   // conv bias cancels in training-mode BN
}

// Bmt[n][i] = Bm[i][n]*sc[i] ; biasu[n] = shift@Bm + beta@A'
__global__ void build_bm(const float* __restrict__ Bm, const float* __restrict__ scsh,
                         const float* __restrict__ cbeta,
                         bf16* __restrict__ Bmt, float* __restrict__ biasu) {
  long idx = (long)blockIdx.x * 256 + threadIdx.x;
  if (idx < 262144) {
    long n = idx >> 9, i = idx & 511;
    Bmt[idx] = __float2bfloat16(Bm[i * 512 + n] * scsh[i]);
  } else if (idx < 262656) {
    int n = (int)(idx - 262144);
    float acc = cbeta[n];
    for (int i = 0; i < 512; ++i) acc += scsh[512 + i] * Bm[(long)i * 512 + n];
    biasu[n] = acc;
  }
}

// ---------------- MFMA scan (operand-swapped): w^T = A'^T @ z^T + U ----------------
// 4 WGs x 16 batches; 8 waves (2/SIMD), each owns a 64-wide n slice (4 mt tiles).
// A kt0..9 in regs (160 VGPR); kt10..15 streamed from L2 each step via asm loads
// with counted vmcnt (<=2 batches in flight). red: conflict-free float2[8*17].
__global__ __launch_bounds__(512, 2)
void krec3(const _Float16* __restrict__ Afrag,  // frag-ordered diag(g)A, 262144 f16
           const ushort* __restrict__ U2,       // bf16 bits, [t][b][n]
           const float* __restrict__ cbeta,     // beta@A (t=0 correction)
           _Float16* __restrict__ S) {          // f16 z, [b*2048+t][512]
  const int tid = threadIdx.x;
  const int lane = tid & 63, w = tid >> 6;      // w in [0,8)
  const int q = lane >> 4, c = lane & 15;
  const int g = blockIdx.x;

  __shared__ _Float16 slds[16 * 520] __attribute__((aligned(16)));  // [batch][n+pad]
  __shared__ float2 red[8 * 17] __attribute__((aligned(16)));       // [w][c], pad 17

  // A k-tiles 0..9 resident in regs: 4 mt x 10 kt = 160 VGPR/AGPR
  f16x8 Ar[40];
#pragma unroll
  for (int mt = 0; mt < 4; ++mt)
#pragma unroll
    for (int kt = 0; kt < 10; ++kt)
      Ar[mt * 10 + kt] = *(const f16x8*)(Afrag + (((w * 4 + mt) * 16 + kt) * 64 + lane) * 8);

  // per-mt base pointers for kt10..15 global streams (rebased at kt12: imm +-4KB)
  const _Float16* ab0 = Afrag + (((w * 4 + 0) * 16 + 12) * 64 + lane) * 8;
  const _Float16* ab1 = Afrag + (((w * 4 + 1) * 16 + 12) * 64 + lane) * 8;
  const _Float16* ab2 = Afrag + (((w * 4 + 2) * 16 + 12) * 64 + lane) * 8;
  const _Float16* ab3 = Afrag + (((w * 4 + 3) * 16 + 12) * 64 + lane) * 8;
#define ISSUE_A(fr, IMM) do { gload_a<IMM>(fr[0], ab0); gload_a<IMM>(fr[1], ab1); \
                              gload_a<IMM>(fr[2], ab2); gload_a<IMM>(fr[3], ab3); } while (0)
#define MFMA_AR(kt) do { \
    f16x8 sf = *(const f16x8*)&slds[c * 520 + (kt) * 32 + q * 8]; \
    acc[0] = __builtin_amdgcn_mfma_f32_16x16x32_f16(Ar[0 * 10 + (kt)], sf, acc[0], 0, 0, 0); \
    acc[1] = __builtin_amdgcn_mfma_f32_16x16x32_f16(Ar[1 * 10 + (kt)], sf, acc[1], 0, 0, 0); \
    acc[2] = __builtin_amdgcn_mfma_f32_16x16x32_f16(Ar[2 * 10 + (kt)], sf, acc[2], 0, 0, 0); \
    acc[3] = __builtin_amdgcn_mfma_f32_16x16x32_f16(Ar[3 * 10 + (kt)], sf, acc[3], 0, 0, 0); } while (0)
#define MFMA_GL(fr, kt) do { \
    f16x8 sf = *(const f16x8*)&slds[c * 520 + (kt) * 32 + q * 8]; \
    acc[0] = __builtin_amdgcn_mfma_f32_16x16x32_f16(fr[0], sf, acc[0], 0, 0, 0); \
    acc[1] = __builtin_amdgcn_mfma_f32_16x16x32_f16(fr[1], sf, acc[1], 0, 0, 0); \
    acc[2] = __builtin_amdgcn_mfma_f32_16x16x32_f16(fr[2], sf, acc[2], 0, 0, 0); \
    acc[3] = __builtin_amdgcn_mfma_f32_16x16x32_f16(fr[3], sf, acc[3], 0, 0, 0); } while (0)

  for (int i = tid; i < 16 * 520; i += 512) slds[i] = (_Float16)0;

  const int nb = w * 64 + q * 4;  // this lane's n-base (plus mt*16)
  // U prefetch for t=0 (asm, drained by WAITV(0) below)
  const ushort* uptr = U2 + ((size_t)(g * 16 + c)) * 512 + nb;  // row g*16+c, t=0
  uint2 upre[4];
#pragma unroll
  for (int mt = 0; mt < 4; ++mt) gload_u2(upre[mt], uptr + mt * 16);
  uptr += 32768;  // advance to t=1 ([t][b][n]: 64*512 per t)
  // z(t-1) store pointers (advance 512 f16 per step)
  _Float16* sp0 = S + ((size_t)(g * 16 + w * 2 + 0) * 2048) * 512 + lane * 8;
  _Float16* sp1 = S + ((size_t)(g * 16 + w * 2 + 1) * 2048) * 512 + lane * 8;

  WAITV(0);         // upre(t=0) resident (asm loads invisible to compiler waits)
  __syncthreads();  // slds zero visible

#pragma unroll 1
  for (int t = 0; t < 2048; ++t) {
    // z(t-1) global stores (reads slds written before BAR2 of t-1)
    if (t > 0) {
      f16x8 v0 = *(const f16x8*)&slds[(w * 2 + 0) * 520 + lane * 8];
      f16x8 v1 = *(const f16x8*)&slds[(w * 2 + 1) * 520 + lane * 8];
      gstore8(sp0, v0); gstore8(sp1, v1);
      sp0 += 512; sp1 += 512;
    }
    WAITV(2);  // U(t) done (oldest); the 2 stores may remain in flight
    // acc init = U_t (bf16 -> f32); rows r = consecutive n
    f32x4v acc[4];
#pragma unroll
    for (int mt = 0; mt < 4; ++mt) {
      uint2 u = upre[mt];
      acc[mt][0] = bflo(u.x); acc[mt][1] = bfhi(u.x);
      acc[mt][2] = bflo(u.y); acc[mt][3] = bfhi(u.y);
    }
    if (t == 0) {  // remove beta@A fold (s_{-1}=0, not an LN output)
#pragma unroll
      for (int mt = 0; mt < 4; ++mt) {
        float4 cb = *(const float4*)(cbeta + nb + mt * 16);
        acc[mt][0] -= cb.x; acc[mt][1] -= cb.y; acc[mt][2] -= cb.z; acc[mt][3] -= cb.w;
      }
    }
    // --- K-loop: Ar kt0..9 interleaved with L2 streams of kt10..15 ---
    // vmcnt waits = count of VMEM ops issued AFTER the batch being consumed.
    f16x8 fA[4], fB[4], fC[4], fD[4], fE[4], fF[4];
    ISSUE_A(fA, -2048);            // kt10
    MFMA_AR(0); MFMA_AR(1);
    ISSUE_A(fB, -1024);            // kt11
    MFMA_AR(2); MFMA_AR(3);
    WAITV(4); MFMA_GL(fA, 10);
    ISSUE_A(fC, 0);                // kt12
    MFMA_AR(4); MFMA_AR(5);
    WAITV(4); MFMA_GL(fB, 11);
    ISSUE_A(fD, 1024);             // kt13
    MFMA_AR(6); MFMA_AR(7);
    WAITV(4); MFMA_GL(fC, 12);
    ISSUE_A(fE, 2048);             // kt14
    MFMA_AR(8); MFMA_AR(9);
    WAITV(4); MFMA_GL(fD, 13);
    ISSUE_A(fF, 3072);             // kt15
    // U prefetch t+1 (issued after all af; never drained mid-step).
    // At t=2047 reads 64KB past U2 end — within bufA slack (131KB), never used.
#pragma unroll
    for (int mt = 0; mt < 4; ++mt) gload_u2(upre[mt], uptr + mt * 16);
    uptr += 32768;
    WAITV(8); MFMA_GL(fE, 14);     // younger-than-fE = fF(4)+U(4)
    WAITV(4); MFMA_GL(fF, 15);     // younger-than-fF = U(4)
    // LN stats for batch c: tree partials in-reg, cross-lane over q via shfl_xor
    float s0 = 0.f, s1 = 0.f, q0 = 0.f, q1 = 0.f;
#pragma unroll
    for (int mt = 0; mt < 4; ++mt) {
      float a0 = acc[mt][0], a1 = acc[mt][1], a2 = acc[mt][2], a3 = acc[mt][3];
      s0 += a0 + a2; s1 += a1 + a3;
      q0 = fmaf(a0, a0, fmaf(a2, a2, q0));
      q1 = fmaf(a1, a1, fmaf(a3, a3, q1));
    }
    float Sv = s0 + s1, Qv = q0 + q1;
    Sv += __shfl_xor(Sv, 16); Sv += __shfl_xor(Sv, 32);
    Qv += __shfl_xor(Qv, 16); Qv += __shfl_xor(Qv, 32);
    if (q == 0) red[w * 17 + c] = make_float2(Sv, Qv);
    ASM_BAR();  // barrier 1: red visible; slds reads of step t done
    // conflict-free tree reduce over 8 wave-partials (b64 broadcasts)
    float2 r0 = red[0 * 17 + c], r1 = red[1 * 17 + c];
    float2 r2 = red[2 * 17 + c], r3 = red[3 * 17 + c];
    float2 r4 = red[4 * 17 + c], r5 = red[5 * 17 + c];
    float2 r6 = red[6 * 17 + c], r7 = red[7 * 17 + c];
    const float fs = ((r0.x + r1.x) + (r2.x + r3.x)) + ((r4.x + r5.x) + (r6.x + r7.x));
    const float fq = ((r0.y + r1.y) + (r2.y + r3.y)) + ((r4.y + r5.y) + (r6.y + r7.y));
    const float mu = fs * (1.f / 512.f);
    const float rs = rsqrtf(fq * (1.f / 512.f) - mu * mu + 1e-5f);
    const float off = -mu * rs;
    // z = (w-mu)*rs -> slds as f16x4 (one b64 per mt)
#pragma unroll
    for (int mt = 0; mt < 4; ++mt) {
      f16x4 pk;
#pragma unroll
      for (int r = 0; r < 4; ++r) pk[r] = (_Float16)fmaf(acc[mt][r], rs, off);
      *(f16x4*)&slds[c * 520 + nb + mt * 16] = pk;
    }
    ASM_BAR();  // barrier 2: z(t) visible for step t+1
  }
  // tail: store z(2047) (C++ stores -> compiler handles end-of-kernel waits)
#pragma unroll
  for (int r = 0; r < 2; ++r) {
    f16x8 v = *(const f16x8*)&slds[(w * 2 + r) * 520 + lane * 8];
    *(f16x8*)(S + ((size_t)(g * 16 + w * 2 + r) * 2048 + 2047) * 512 + lane * 8) = v;
  }
#undef ISSUE_A
#undef MFMA_AR
#undef MFMA_GL
}

// ---------------- host launch ----------------
extern "C" void kernel_launch(void* const* d_in, const int* in_sizes, int n_in,
                              void* d_out, int out_size, void* d_ws, size_t ws_size,
                              hipStream_t stream) {
  (void)in_sizes; (void)n_in; (void)out_size; (void)ws_size;
  const float* x     = (const float*)d_in[0];
  const float* W_in  = (const float*)d_in[1];
  const float* b_in  = (const float*)d_in[2];
  const float* convw = (const float*)d_in[3];
  // d_in[4] conv_b: cancels in training-mode BN
  const float* bng   = (const float*)d_in[5];
  const float* bnb   = (const float*)d_in[6];
  const float* lng   = (const float*)d_in[7];
  const float* lnb   = (const float*)d_in[8];
  const float* Am    = (const float*)d_in[9];
  const float* Bm    = (const float*)d_in[10];
  const float* Cm    = (const float*)d_in[11];

  char* ws = (char*)d_ws;
  bf16*      xb    = (bf16*)(ws + 0ull);             // 67,108,864 B
  bf16*      bufA  = (bf16*)(ws + 67108864ull);      // 134,348,800 B: vpad -> U2[t][b][n]
  bf16*      bufB  = (bf16*)(ws + 201457664ull);     // 134,217,728 B: craw -> S (f16)
  bf16*      Wt    = (bf16*)(ws + 335675392ull);     // 262,144
  bf16*      Wct   = (bf16*)(ws + 335937536ull);     // 1,572,864
  _Float16*  Afr   = (_Float16*)(ws + 337510400ull); // 524,288
  _Float16*  Ctf   = (_Float16*)(ws + 338034688ull); // 262,144
  bf16*      Bmt   = (bf16*)(ws + 338296832ull);     // 524,288
  float*     biasu = (float*)(ws + 338821120ull);    // 2,048
  float*     sums  = (float*)(ws + 338823168ull);    // 4,096
  float*     scsh  = (float*)(ws + 338827264ull);    // 4,096
  float*     cbeta = (float*)(ws + 338831360ull);    // 2,048
  float*     ybeta = (float*)(ws + 338833408ull);    // 1,024   (end ~323 MiB)

  kprep<<<5383, 256, 0, stream>>>(W_in, convw, Am, Cm, lng, lnb, sums, bufA, Wt, Wct, Ctf, Afr,
                                  cbeta, ybeta);
  kx<<<32768, 256, 0, stream>>>((const float4*)x, (ushort4*)xb);
  // G1: v = silu(x @ W_in^T + b)  -> vpad interior
  kgemm<0, false><<<dim3(1024, 4), 256, 0, stream>>>(xb, 256, 0, Wt, 256, b_in, bufA);
  // G2: conv as GEMM over 1536-wide windows of vpad (row skew for padding)
  kgemm<1, false><<<dim3(1024, 4), 256, 0, stream>>>(bufA, 512, 1024, Wct, 1536, nullptr, bufB);
  bn_stats<<<1024, 512, 0, stream>>>(bufB, sums);
  bn_finalize<<<1, 512, 0, stream>>>(sums, bng, bnb, scsh);
  build_bm<<<1026, 256, 0, stream>>>(Bm, scsh, cbeta, Bmt, biasu);
  // G3: U = craw @ (diag(sc)Bm) + biasu  -> bufA as [t][b][n] (vpad dead)
  kgemm<2, false><<<dim3(1024, 4), 256, 0, stream>>>(bufB, 512, 0, Bmt, 512, biasu, bufA);
  // MFMA scan -> z into bufB (craw dead); 8 waves, 2 waves/SIMD
  krec3<<<4, 512, 0, stream>>>(Afr, (const ushort*)bufA, cbeta, (_Float16*)bufB);
  // G4: Y = z @ (diag(g)C) + beta@C -> d_out fp32
  kgemm<3, true><<<dim3(1024, 2), 256, 0, stream>>>(bufB, 512, 0, (const bf16*)Ctf, 512, ybeta, d_out);
}

// Round 3
// 5910.888 us; speedup vs baseline: 2.3694x; 2.3694x over previous
//
#include <hip/hip_runtime.h>
#include <hip/hip_bf16.h>
#include <hip/hip_fp16.h>
#include <stdint.h>

// MambaBlock: B=64 T=2048 IN=256 STATE=512 OUT=256 K=3
// prep -> x->bf16 -> G1(silu proj) -> G2(conv-as-GEMM) -> BN stats
//      -> fold BN into Bm -> G3(U = conv_raw@Bm'+bias, [t][b][n] layout)
//      -> MFMA scan (8-wave, 2 waves/SIMD; conflict-free red; asm barriers)
//      -> G4(Y = S@C', f16, +beta@C bias)

using bf16 = __hip_bfloat16;
typedef short    bf16x8 __attribute__((ext_vector_type(8)));
typedef float    f32x4v __attribute__((ext_vector_type(4)));
typedef _Float16 f16x8  __attribute__((ext_vector_type(8)));
typedef _Float16 f16x4  __attribute__((ext_vector_type(4)));

static __device__ inline unsigned short f2bf_bits(float f) {
  union { bf16 h; unsigned short u; } cv; cv.h = __float2bfloat16(f); return cv.u;
}
static __device__ inline float bflo(unsigned v) { return __builtin_bit_cast(float, v << 16); }
static __device__ inline float bfhi(unsigned v) { return __builtin_bit_cast(float, v & 0xFFFF0000u); }

// async global->LDS, 16B/lane; LDS dest = wave-uniform base + lane*16
static __device__ inline void glds16(const void* g, void* l) {
  __builtin_amdgcn_global_load_lds(
      (const __attribute__((address_space(1))) unsigned int*)g,
      (__attribute__((address_space(3))) unsigned int*)l, 16, 0, 0);
}

// barrier that drains ONLY lgkm (LDS) — leaves global loads/stores in flight.
// All cross-wave data flows through LDS, so this is sufficient for krec2.
#define ASM_BAR() asm volatile("s_waitcnt lgkmcnt(0)\n\ts_barrier" ::: "memory")

// ---------------- prep: zero sums + vpad edges, build weights ----------------
__global__ void kprep(const float* __restrict__ W_in, const float* __restrict__ conv_w,
                      const float* __restrict__ A, const float* __restrict__ C,
                      const float* __restrict__ lng, const float* __restrict__ lnb,
                      float* __restrict__ sums, bf16* __restrict__ vpad,
                      bf16* __restrict__ Wt, bf16* __restrict__ Wct,
                      _Float16* __restrict__ Ctf, _Float16* __restrict__ Afr,
                      float* __restrict__ cbeta, float* __restrict__ ybeta) {
  long idx = (long)blockIdx.x * 256 + threadIdx.x;
  if (idx < 1024) { sums[idx] = 0.f; return; }
  idx -= 1024;
  if (idx < 65536) {  // zero pad rows (t=-1, t=T) of vpad (64 x 2050 x 512)
    long b = idx >> 10, rem = idx & 1023, r = rem >> 9, col = rem & 511;
    long row = b * 2050 + (r ? 2049 : 0);
    vpad[row * 512 + col] = __float2bfloat16(0.f);
    return;
  }
  idx -= 65536;
  if (idx < 131072) { Wt[idx] = __float2bfloat16(W_in[idx]); return; } // (N=512,K=256)
  idx -= 131072;
  if (idx < 786432) { // Wct[o][kk*512+i] = conv_w[o,i,kk]   (N=512, K=1536)
    long o = idx / 1536, k = idx - o * 1536, kk = k >> 9, i = k & 511;
    Wct[idx] = __float2bfloat16(conv_w[(o * 512 + i) * 3 + kk]);
    return;
  }
  idx -= 786432;
  if (idx < 131072) { // Ctf[n][i] = C[i][n]*gamma[i]  f16  (N=256, K=512)
    long n = idx >> 9, i = idx & 511;
    Ctf[idx] = (_Float16)(C[i * 256 + n] * lng[i]);
    return;
  }
  idx -= 131072;
  if (idx < 262144) { // A' = diag(gamma)A -> MFMA fragment order (f16)
    long k = idx >> 9, n = idx & 511;
    long w = n >> 7, nt = (n >> 4) & 7, cc = n & 15;
    long kt = k >> 5, qq = (k & 31) >> 3, j = k & 7;
    Afr[(((w * 8 + nt) * 16 + kt) * 64 + (qq * 16 + cc)) * 8 + j] =
        (_Float16)(A[k * 512 + n] * lng[k]);
    return;
  }
  idx -= 262144;
  if (idx < 512) { // cbeta[n] = sum_k beta[k]*A[k][n]
    int n = (int)idx;
    float acc = 0.f;
    for (int k = 0; k < 512; ++k) acc += lnb[k] * A[(long)k * 512 + n];
    cbeta[n] = acc;
    return;
  }
  idx -= 512;
  if (idx < 256) { // ybeta[n] = sum_i beta[i]*C[i][n]
    int n = (int)idx;
    float acc = 0.f;
    for (int i = 0; i < 512; ++i) acc += lnb[i] * C[(long)i * 256 + n];
    ybeta[n] = acc;
  }
}

// ---------------- x fp32 -> bf16 ----------------
__global__ void kx(const float4* __restrict__ x, ushort4* __restrict__ xb) {
  size_t i = (size_t)blockIdx.x * 256 + threadIdx.x;
  float4 v = x[i];
  ushort4 o;
  o.x = f2bf_bits(v.x); o.y = f2bf_bits(v.y); o.z = f2bf_bits(v.z); o.w = f2bf_bits(v.w);
  xb[i] = o;
}

// ---------------- 128x128 MFMA GEMM, BK=64, 4 waves ----------------
// EPI 0: +bias, silu -> vpad scatter   EPI 1: bf16 (stride 512)
// EPI 2: +bias, bf16 -> U[t][b][n]     EPI 3: +bias, fp32 (stride 256)
template <int EPI, bool F16>
__global__ __launch_bounds__(256)
void kgemm(const bf16* __restrict__ Ag, long lda, long rowExtra,
           const bf16* __restrict__ Bg, int K,
           const float* __restrict__ bias, void* __restrict__ outp) {
  const int tid = threadIdx.x;
  const int lane = tid & 63;
  const int wv = tid >> 6;
  const int wm = wv >> 1, wn = wv & 1;
  const long m0 = (long)blockIdx.x * 128;
  const long n0 = (long)blockIdx.y * 128;
  __shared__ short At[128 * 64];
  __shared__ short Bt[128 * 64];
  f32x4v acc[4][4];
#pragma unroll
  for (int a = 0; a < 4; ++a)
#pragma unroll
    for (int b = 0; b < 4; ++b)
#pragma unroll
      for (int r = 0; r < 4; ++r) acc[a][b][r] = 0.f;

  const int rsub = lane >> 3;
  const int ksub = (lane & 7) * 8;

  for (int k0 = 0; k0 < K; k0 += 64) {
#pragma unroll
    for (int j = 0; j < 4; ++j) {
      const int c = wv * 4 + j;
      {
        long row = m0 + c * 8 + rsub;
        const bf16* gp = Ag + row * lda + (row >> 11) * rowExtra + k0 + ksub;
        glds16(gp, At + c * 512);
      }
      {
        long row = n0 + c * 8 + rsub;
        const bf16* gp = Bg + row * (long)K + k0 + ksub;
        glds16(gp, Bt + c * 512);
      }
    }
    __syncthreads();
#pragma unroll
    for (int h = 0; h < 2; ++h) {
      bf16x8 af[4], bf_[4];
      const int kb = h * 32 + (lane >> 4) * 8;
#pragma unroll
      for (int f = 0; f < 4; ++f) {
        af[f]  = *(const bf16x8*)(At + (wm * 64 + f * 16 + (lane & 15)) * 64 + kb);
        bf_[f] = *(const bf16x8*)(Bt + (wn * 64 + f * 16 + (lane & 15)) * 64 + kb);
      }
#pragma unroll
      for (int fm = 0; fm < 4; ++fm)
#pragma unroll
        for (int fn = 0; fn < 4; ++fn) {
          if constexpr (F16)
            acc[fm][fn] = __builtin_amdgcn_mfma_f32_16x16x32_f16(
                __builtin_bit_cast(f16x8, af[fm]), __builtin_bit_cast(f16x8, bf_[fn]),
                acc[fm][fn], 0, 0, 0);
          else
            acc[fm][fn] = __builtin_amdgcn_mfma_f32_16x16x32_bf16(af[fm], bf_[fn], acc[fm][fn], 0, 0, 0);
        }
    }
    __syncthreads();
  }

  const int q = lane >> 4, cL = lane & 15;
#pragma unroll
  for (int fm = 0; fm < 4; ++fm)
#pragma unroll
    for (int fn = 0; fn < 4; ++fn)
#pragma unroll
      for (int r = 0; r < 4; ++r) {
        const long m = m0 + wm * 64 + fm * 16 + q * 4 + r;
        const long n = n0 + wn * 64 + fn * 16 + cL;
        float v = acc[fm][fn][r];
        if constexpr (EPI == 0) {
          v += bias[n];
          const float s = v / (1.f + __expf(-v));
          const long row = (m >> 11) * 2050 + (m & 2047) + 1;
          ((bf16*)outp)[row * 512 + n] = __float2bfloat16(s);
        } else if constexpr (EPI == 1) {
          ((bf16*)outp)[m * 512 + n] = __float2bfloat16(v);
        } else if constexpr (EPI == 2) {
          // U layout [t][b][n]: m = b*2048+t  ->  row' = t*64 + b
          const long rowp = (m & 2047) * 64 + (m >> 11);
          ((bf16*)outp)[rowp * 512 + n] = __float2bfloat16(v + bias[n]);
        } else {
          ((float*)outp)[m * 256 + n] = v + bias[n];
        }
      }
}

// ---------------- BN stats ----------------
__global__ __launch_bounds__(512)
void bn_stats(const bf16* __restrict__ cr, float* __restrict__ sums) {
  const int tid = threadIdx.x;
  const long base = (long)blockIdx.x * 128 * 512;
  float s = 0.f, q = 0.f;
  for (int r = 0; r < 128; ++r) {
    float v = __bfloat162float(cr[base + (long)r * 512 + tid]);
    s += v; q += v * v;
  }
  atomicAdd(&sums[tid], s);
  atomicAdd(&sums[512 + tid], q);
}

__global__ void bn_finalize(const float* __restrict__ sums, const float* __restrict__ gamma,
                            const float* __restrict__ beta, float* __restrict__ scsh) {
  const int n = threadIdx.x;
  const float mu = sums[n] * (1.f / 131072.f);
  const float var = sums[512 + n] * (1.f / 131072.f) - mu * mu;
  const float sc = gamma[n] * rsqrtf(var + 1e-5f);
  scsh[n] = sc;
  scsh[512 + n] = beta[n] - mu * sc;   // conv bias cancels in training-mode BN
}

// Bmt[n][i] = Bm[i][n]*sc[i] ; biasu[n] = shift@Bm + beta@A'
__global__ void build_bm(const float* __restrict__ Bm, const float* __restrict__ scsh,
                         const float* __restrict__ cbeta,
                         bf16* __restrict__ Bmt, float* __restrict__ biasu) {
  long idx = (long)blockIdx.x * 256 + threadIdx.x;
  if (idx < 262144) {
    long n = idx >> 9, i = idx & 511;
    Bmt[idx] = __float2bfloat16(Bm[i * 512 + n] * scsh[i]);
  } else if (idx < 262656) {
    int n = (int)(idx - 262144);
    float acc = cbeta[n];
    for (int i = 0; i < 512; ++i) acc += scsh[512 + i] * Bm[(long)i * 512 + n];
    biasu[n] = acc;
  }
}

// ---------------- MFMA scan (operand-swapped): w^T = A'^T @ z^T + U ----------------
// 4 WGs x 16 batches; 8 waves (2 waves/SIMD) — each wave owns a 64-wide n slice.
// z = (w-mu)*rsig stored (gamma/beta folded into A', C', biases).
// red layout [w][c] pad-17 float2: write banks 2w+2c (conflict-free),
// read 8x b64 broadcast tree (conflict-free) — replaces 8-way-conflicted float4 path.
__global__ __launch_bounds__(512, 2)
void krec2(const _Float16* __restrict__ Afrag,  // frag-ordered diag(g)A, 262144 f16
           const ushort* __restrict__ U2,       // bf16 bits, [t][b][n]
           const float* __restrict__ cbeta,     // beta@A (t=0 correction)
           _Float16* __restrict__ S) {          // f16 z, [b*2048+t][512]
  const int tid = threadIdx.x;
  const int lane = tid & 63, w = tid >> 6;      // w in [0,8)
  const int q = lane >> 4, c = lane & 15;
  const int g = blockIdx.x;

  __shared__ _Float16 Alds[128 * 512] __attribute__((aligned(16)));  // 128 KB: kt 12..15
  __shared__ _Float16 slds[16 * 520] __attribute__((aligned(16)));   // [batch][n+pad]
  __shared__ float2 red[8 * 17] __attribute__((aligned(16)));        // [w][c], pad 17

  // A k-tiles 0..11 resident in VGPR/AGPR (192 regs): 4 mt x 12 kt
  f16x8 Ar[48];
#pragma unroll
  for (int mt = 0; mt < 4; ++mt)
#pragma unroll
    for (int kt = 0; kt < 12; ++kt)
      Ar[mt * 12 + kt] = *(const f16x8*)(Afrag + (((w * 4 + mt) * 16 + kt) * 64 + lane) * 8);

  // k-tiles 12..15 -> LDS via async copy (frag layout: lane*16B)
#pragma unroll
  for (int mt = 0; mt < 4; ++mt)
#pragma unroll
    for (int k2 = 0; k2 < 4; ++k2)
      glds16(Afrag + (((w * 4 + mt) * 16 + 12 + k2) * 64 + lane) * 8,
             &Alds[((w * 4 + mt) * 4 + k2) * 512]);

  for (int i = tid; i < 16 * 520; i += 512) slds[i] = (_Float16)0;

  const int nb = w * 64 + q * 4;  // this lane's n-base (plus mt*16)
  // U prefetch for t=0
  uint2 upre[4];
#pragma unroll
  for (int mt = 0; mt < 4; ++mt)
    upre[mt] = *(const uint2*)(U2 + ((size_t)(g * 16 + c)) * 512 + nb + mt * 16);
  __syncthreads();  // drains glds16 (vmcnt) + slds zero visible

#pragma unroll 1
  for (int t = 0; t < 2048; ++t) {
    // acc init = U_t (bf16 -> f32); rows r = consecutive n
    f32x4v acc[4];
#pragma unroll
    for (int mt = 0; mt < 4; ++mt) {
      uint2 u = upre[mt];
      acc[mt][0] = bflo(u.x); acc[mt][1] = bfhi(u.x);
      acc[mt][2] = bflo(u.y); acc[mt][3] = bfhi(u.y);
    }
    if (t == 0) {  // remove beta@A fold (s_{-1}=0, not an LN output)
#pragma unroll
      for (int mt = 0; mt < 4; ++mt) {
        float4 cb = *(const float4*)(cbeta + nb + mt * 16);
        acc[mt][0] -= cb.x; acc[mt][1] -= cb.y; acc[mt][2] -= cb.z; acc[mt][3] -= cb.w;
      }
    }
    // prefetch U_{t+1} (stays in flight across asm barriers)
    const int tnx = (t < 2047) ? t + 1 : 2047;
#pragma unroll
    for (int mt = 0; mt < 4; ++mt)
      upre[mt] = *(const uint2*)(U2 + ((size_t)tnx * 64 + g * 16 + c) * 512 + nb + mt * 16);
    // MFMA: A'-tiles (A-operand) x z-frags (B-operand, read from slds)
#pragma unroll
    for (int kt = 0; kt < 12; ++kt) {
      f16x8 sf = *(const f16x8*)&slds[c * 520 + kt * 32 + q * 8];
#pragma unroll
      for (int mt = 0; mt < 4; ++mt)
        acc[mt] = __builtin_amdgcn_mfma_f32_16x16x32_f16(Ar[mt * 12 + kt], sf, acc[mt], 0, 0, 0);
    }
#pragma unroll
    for (int k2 = 0; k2 < 4; ++k2) {
      f16x8 sf = *(const f16x8*)&slds[c * 520 + (12 + k2) * 32 + q * 8];
#pragma unroll
      for (int mt = 0; mt < 4; ++mt) {
        f16x8 af = *(const f16x8*)&Alds[((w * 4 + mt) * 4 + k2) * 512 + lane * 8];
        acc[mt] = __builtin_amdgcn_mfma_f32_16x16x32_f16(af, sf, acc[mt], 0, 0, 0);
      }
    }
    // LN stats for batch c: tree partials in-reg, cross-lane over q via shfl_xor
    float s0 = 0.f, s1 = 0.f, q0 = 0.f, q1 = 0.f;
#pragma unroll
    for (int mt = 0; mt < 4; ++mt) {
      float a0 = acc[mt][0], a1 = acc[mt][1], a2 = acc[mt][2], a3 = acc[mt][3];
      s0 += a0 + a2; s1 += a1 + a3;
      q0 = fmaf(a0, a0, fmaf(a2, a2, q0));
      q1 = fmaf(a1, a1, fmaf(a3, a3, q1));
    }
    float Sv = s0 + s1, Qv = q0 + q1;
    Sv += __shfl_xor(Sv, 16); Sv += __shfl_xor(Sv, 32);
    Qv += __shfl_xor(Qv, 16); Qv += __shfl_xor(Qv, 32);
    if (q == 0) red[w * 17 + c] = make_float2(Sv, Qv);
    // store z(t-1) from slds (coalesced b128) in the pre-barrier window
    if (t > 0) {
#pragma unroll
      for (int r = 0; r < 2; ++r) {
        f16x8 v = *(const f16x8*)&slds[(w * 2 + r) * 520 + lane * 8];
        *(f16x8*)(S + ((size_t)(g * 16 + w * 2 + r) * 2048 + (t - 1)) * 512 + lane * 8) = v;
      }
    }
    ASM_BAR();  // barrier 1: red visible; slds reads of step t done
    // conflict-free tree reduce over 8 wave-partials (b64 broadcasts)
    float2 r0 = red[0 * 17 + c], r1 = red[1 * 17 + c];
    float2 r2 = red[2 * 17 + c], r3 = red[3 * 17 + c];
    float2 r4 = red[4 * 17 + c], r5 = red[5 * 17 + c];
    float2 r6 = red[6 * 17 + c], r7 = red[7 * 17 + c];
    const float fs = ((r0.x + r1.x) + (r2.x + r3.x)) + ((r4.x + r5.x) + (r6.x + r7.x));
    const float fq = ((r0.y + r1.y) + (r2.y + r3.y)) + ((r4.y + r5.y) + (r6.y + r7.y));
    const float mu = fs * (1.f / 512.f);
    const float rs = rsqrtf(fq * (1.f / 512.f) - mu * mu + 1e-5f);
    const float off = -mu * rs;
    // z = (w-mu)*rs -> slds as f16x4 (one b64 per mt)
#pragma unroll
    for (int mt = 0; mt < 4; ++mt) {
      f16x4 pk;
#pragma unroll
      for (int r = 0; r < 4; ++r) pk[r] = (_Float16)fmaf(acc[mt][r], rs, off);
      *(f16x4*)&slds[c * 520 + nb + mt * 16] = pk;
    }
    ASM_BAR();  // barrier 2: z(t) visible for step t+1
  }
  // tail: store z(2047)
#pragma unroll
  for (int r = 0; r < 2; ++r) {
    f16x8 v = *(const f16x8*)&slds[(w * 2 + r) * 520 + lane * 8];
    *(f16x8*)(S + ((size_t)(g * 16 + w * 2 + r) * 2048 + 2047) * 512 + lane * 8) = v;
  }
}

// ---------------- host launch ----------------
extern "C" void kernel_launch(void* const* d_in, const int* in_sizes, int n_in,
                              void* d_out, int out_size, void* d_ws, size_t ws_size,
                              hipStream_t stream) {
  (void)in_sizes; (void)n_in; (void)out_size; (void)ws_size;
  const float* x     = (const float*)d_in[0];
  const float* W_in  = (const float*)d_in[1];
  const float* b_in  = (const float*)d_in[2];
  const float* convw = (const float*)d_in[3];
  // d_in[4] conv_b: cancels in training-mode BN
  const float* bng   = (const float*)d_in[5];
  const float* bnb   = (const float*)d_in[6];
  const float* lng   = (const float*)d_in[7];
  const float* lnb   = (const float*)d_in[8];
  const float* Am    = (const float*)d_in[9];
  const float* Bm    = (const float*)d_in[10];
  const float* Cm    = (const float*)d_in[11];

  char* ws = (char*)d_ws;
  bf16*      xb    = (bf16*)(ws + 0ull);             // 67,108,864 B
  bf16*      bufA  = (bf16*)(ws + 67108864ull);      // 134,348,800 B: vpad -> U2[t][b][n]
  bf16*      bufB  = (bf16*)(ws + 201457664ull);     // 134,217,728 B: craw -> S (f16)
  bf16*      Wt    = (bf16*)(ws + 335675392ull);     // 262,144
  bf16*      Wct   = (bf16*)(ws + 335937536ull);     // 1,572,864
  _Float16*  Afr   = (_Float16*)(ws + 337510400ull); // 524,288
  _Float16*  Ctf   = (_Float16*)(ws + 338034688ull); // 262,144
  bf16*      Bmt   = (bf16*)(ws + 338296832ull);     // 524,288
  float*     biasu = (float*)(ws + 338821120ull);    // 2,048
  float*     sums  = (float*)(ws + 338823168ull);    // 4,096
  float*     scsh  = (float*)(ws + 338827264ull);    // 4,096
  float*     cbeta = (float*)(ws + 338831360ull);    // 2,048
  float*     ybeta = (float*)(ws + 338833408ull);    // 1,024   (end ~323 MiB)

  kprep<<<5383, 256, 0, stream>>>(W_in, convw, Am, Cm, lng, lnb, sums, bufA, Wt, Wct, Ctf, Afr,
                                  cbeta, ybeta);
  kx<<<32768, 256, 0, stream>>>((const float4*)x, (ushort4*)xb);
  // G1: v = silu(x @ W_in^T + b)  -> vpad interior
  kgemm<0, false><<<dim3(1024, 4), 256, 0, stream>>>(xb, 256, 0, Wt, 256, b_in, bufA);
  // G2: conv as GEMM over 1536-wide windows of vpad (row skew for padding)
  kgemm<1, false><<<dim3(1024, 4), 256, 0, stream>>>(bufA, 512, 1024, Wct, 1536, nullptr, bufB);
  bn_stats<<<1024, 512, 0, stream>>>(bufB, sums);
  bn_finalize<<<1, 512, 0, stream>>>(sums, bng, bnb, scsh);
  build_bm<<<1026, 256, 0, stream>>>(Bm, scsh, cbeta, Bmt, biasu);
  // G3: U = craw @ (diag(sc)Bm) + biasu  -> bufA as [t][b][n] (vpad dead)
  kgemm<2, false><<<dim3(1024, 4), 256, 0, stream>>>(bufB, 512, 0, Bmt, 512, biasu, bufA);
  // MFMA scan -> z into bufB (craw dead); 8 waves, 2 waves/SIMD
  krec2<<<4, 512, 0, stream>>>(Afr, (const ushort*)bufA, cbeta, (_Float16*)bufB);
  // G4: Y = z @ (diag(g)C) + beta@C -> d_out fp32
  kgemm<3, true><<<dim3(1024, 2), 256, 0, stream>>>(bufB, 512, 0, (const bf16*)Ctf, 512, ybeta, d_out);
}